// Round 1
// baseline (416.104 us; speedup 1.0000x reference)
//
#include <hip/hip_runtime.h>

#define DMODEL 1024
#define DKH 64
#define NH 16
#define DFF 4096
#define BB 2
#define TT 2048
#define ROWS (BB*TT)      // 4096
#define QKVN (3*DMODEL)   // 3072

typedef unsigned short ushort_t;
typedef __attribute__((ext_vector_type(8))) short s8v;
typedef __attribute__((ext_vector_type(4))) float f4v;
typedef __attribute__((ext_vector_type(4))) unsigned short us4v;

typedef const void __attribute__((address_space(1)))* GPTR;
typedef void __attribute__((address_space(3)))* SPTR;

__device__ __forceinline__ float bf2f(ushort_t u) {
  return __uint_as_float(((unsigned int)u) << 16);
}
__device__ __forceinline__ ushort_t f2bf(float f) {
  unsigned int u = __float_as_uint(f);
  u += 0x7fffu + ((u >> 16) & 1u);
  return (ushort_t)(u >> 16);
}
__device__ __forceinline__ void gload16(const void* g, void* l) {
  __builtin_amdgcn_global_load_lds((GPTR)g, (SPTR)l, 16, 0, 0);
}

// ---------------- conversion kernels ----------------
__global__ __launch_bounds__(256) void cvt_f32_bf16(const float* __restrict__ in,
                                                    ushort_t* __restrict__ out, int n4) {
  int i = blockIdx.x * 256 + threadIdx.x;
  if (i >= n4) return;
  float4 v = ((const float4*)in)[i];
  us4v o;
  o.x = f2bf(v.x); o.y = f2bf(v.y); o.z = f2bf(v.z); o.w = f2bf(v.w);
  ((us4v*)out)[i] = o;
}

// in [R,C] f32 -> out [C,R] bf16
__global__ __launch_bounds__(256) void transpose_cvt(const float* __restrict__ in,
                                                     ushort_t* __restrict__ out, int R, int C) {
  __shared__ float tile[32][33];
  int bx = blockIdx.x * 32, by = blockIdx.y * 32;
  int tx = threadIdx.x, ty = threadIdx.y;
#pragma unroll
  for (int i = 0; i < 32; i += 8)
    tile[ty + i][tx] = in[(size_t)(by + ty + i) * C + bx + tx];
  __syncthreads();
#pragma unroll
  for (int i = 0; i < 32; i += 8)
    out[(size_t)(bx + ty + i) * R + by + tx] = f2bf(tile[tx][ty + i]);
}

__global__ void concat_bias(const float* __restrict__ a, const float* __restrict__ b,
                            const float* __restrict__ c, float* __restrict__ o) {
  int i = blockIdx.x * 256 + threadIdx.x;
  if (i < 1024) { o[i] = a[i]; o[1024 + i] = b[i]; o[2048 + i] = c[i]; }
}

// ---------------- GEMM: C[M,N] = A[M,K] @ BT[N,K]^T + bias, bf16 out ----------------
template<bool RELU>
__global__ __launch_bounds__(256) void gemm_bt(const ushort_t* __restrict__ A,
                                               const ushort_t* __restrict__ BT,
                                               const float* __restrict__ bias,
                                               ushort_t* __restrict__ C,
                                               int M, int N, int K) {
  __shared__ __align__(16) ushort_t As[128 * 32];
  __shared__ __align__(16) ushort_t Bs[128 * 32];
  const int tid = threadIdx.x;
  const int w = tid >> 6, l = tid & 63;
  const int m0 = blockIdx.y * 128, n0 = blockIdx.x * 128;
  const int wr = (w >> 1) * 64, wc = (w & 1) * 64;
  const int lr = l & 15, lg = l >> 4;
  const int srow = tid >> 2, sc8 = (tid & 3) * 8;
  f4v acc[4][4] = {};
  for (int kt = 0; kt < K; kt += 32) {
#pragma unroll
    for (int r = 0; r < 2; ++r) {
      int row = r * 64 + srow;
      gload16(A + (size_t)(m0 + row) * K + kt + sc8, (char*)As + (r * 256 + w * 64) * 16);
      gload16(BT + (size_t)(n0 + row) * K + kt + sc8, (char*)Bs + (r * 256 + w * 64) * 16);
    }
    __syncthreads();
    s8v af[4], bf[4];
#pragma unroll
    for (int m = 0; m < 4; ++m)
      af[m] = *(const s8v*)(As + (wr + m * 16 + lr) * 32 + lg * 8);
#pragma unroll
    for (int n = 0; n < 4; ++n)
      bf[n] = *(const s8v*)(Bs + (wc + n * 16 + lr) * 32 + lg * 8);
#pragma unroll
    for (int m = 0; m < 4; ++m)
#pragma unroll
      for (int n = 0; n < 4; ++n)
        acc[m][n] = __builtin_amdgcn_mfma_f32_16x16x32_bf16(af[m], bf[n], acc[m][n], 0, 0, 0);
    __syncthreads();
  }
#pragma unroll
  for (int n = 0; n < 4; ++n) {
    int col = n0 + wc + n * 16 + lr;
    float bv = bias[col];
#pragma unroll
    for (int m = 0; m < 4; ++m) {
      int row = m0 + wr + m * 16 + lg * 4;
#pragma unroll
      for (int j = 0; j < 4; ++j) {
        float v = acc[m][n][j] + bv;
        if (RELU) v = fmaxf(v, 0.f);
        C[(size_t)(row + j) * N + col] = f2bf(v);
      }
    }
  }
}

// ---------------- causal flash attention ----------------
// QKV: [ROWS, 3072] bf16 (cols: 0..1023 Q, 1024..2047 K, 2048..3071 V; col = h*64+d)
// O:   [ROWS, 1024] bf16
__global__ __launch_bounds__(256) void attn_kernel(const ushort_t* __restrict__ QKV,
                                                   ushort_t* __restrict__ O) {
  const int qt = blockIdx.x;
  const int bh = blockIdx.y;
  const int b = bh >> 4, h = bh & 15;
  const int tid = threadIdx.x;
  const int w = tid >> 6, l = tid & 63;
  const int lr = l & 15, lg = l >> 4;

  __shared__ __align__(16) ushort_t Ksh[64 * 64];
  __shared__ __align__(16) ushort_t Vsh[64 * 64];  // transposed: [d][k]
  __shared__ __align__(16) ushort_t Psh[4][16 * 72];

  const size_t RS = QKVN;
  const ushort_t* Qp = QKV + ((size_t)b * TT + qt * 64) * RS + h * 64;
  const ushort_t* Kp = QKV + (size_t)b * TT * RS + DMODEL + h * 64;
  const ushort_t* Vp = Kp + DMODEL;

  s8v qf[2];
  {
    const ushort_t* qrow = Qp + (size_t)(w * 16 + lr) * RS + lg * 8;
    qf[0] = *(const s8v*)(qrow);
    qf[1] = *(const s8v*)(qrow + 32);
  }
  float mrow[4], lrow[4];
  f4v acc[4] = {};
#pragma unroll
  for (int j = 0; j < 4; ++j) { mrow[j] = -__builtin_inff(); lrow[j] = 0.f; }

  for (int kt = 0; kt <= qt; ++kt) {
    // stage K (row-swizzled) and V^T (row-swizzled)
#pragma unroll
    for (int r = 0; r < 2; ++r) {
      int id = r * 256 + tid;
      int kl = id >> 3, d0 = (id & 7) * 8;
      const size_t gk = (size_t)(kt * 64 + kl) * RS + d0;
      s8v kv = *(const s8v*)(Kp + gk);
      int kb = (kl * 128 + d0 * 2) ^ ((kl & 7) << 4);
      *(s8v*)((char*)Ksh + kb) = kv;
      s8v vv = *(const s8v*)(Vp + gk);
#pragma unroll
      for (int j2 = 0; j2 < 8; ++j2) {
        int d = d0 + j2;
        int vb = (d * 128 + kl * 2) ^ ((d & 7) << 4);
        *(ushort_t*)((char*)Vsh + vb) = (ushort_t)vv[j2];
      }
    }
    __syncthreads();

    // S = Q K^T  (16 q-rows x 64 k-cols per wave)
    float p[4][4];
#pragma unroll
    for (int c = 0; c < 4; ++c) {
      f4v a = {};
#pragma unroll
      for (int kk = 0; kk < 2; ++kk) {
        int rr = c * 16 + lr;
        int byte = (rr * 128 + kk * 64 + lg * 16) ^ ((rr & 7) << 4);
        s8v kf = *(const s8v*)((const char*)Ksh + byte);
        a = __builtin_amdgcn_mfma_f32_16x16x32_bf16(qf[kk], kf, a, 0, 0, 0);
      }
#pragma unroll
      for (int j = 0; j < 4; ++j) p[c][j] = a[j] * 0.125f;
    }
    if (kt == qt) {
#pragma unroll
      for (int c = 0; c < 4; ++c) {
        int kl_ = c * 16 + lr;
#pragma unroll
        for (int j = 0; j < 4; ++j) {
          int ql_ = w * 16 + lg * 4 + j;
          if (kl_ > ql_) p[c][j] = -__builtin_inff();
        }
      }
    }
    // row max over 64 cols (cols live across the 16-lane group)
    float pm[4];
#pragma unroll
    for (int j = 0; j < 4; ++j)
      pm[j] = fmaxf(fmaxf(p[0][j], p[1][j]), fmaxf(p[2][j], p[3][j]));
#pragma unroll
    for (int off = 1; off <= 8; off <<= 1)
#pragma unroll
      for (int j = 0; j < 4; ++j)
        pm[j] = fmaxf(pm[j], __shfl_xor(pm[j], off));
    float rs_[4];
#pragma unroll
    for (int j = 0; j < 4; ++j) {
      float mn = fmaxf(mrow[j], pm[j]);
      rs_[j] = __expf(mrow[j] - mn);
      mrow[j] = mn;
    }
    float psum[4] = {0.f, 0.f, 0.f, 0.f};
#pragma unroll
    for (int c = 0; c < 4; ++c)
#pragma unroll
      for (int j = 0; j < 4; ++j) {
        float e = __expf(p[c][j] - mrow[j]);
        p[c][j] = e;
        psum[j] += e;
      }
#pragma unroll
    for (int off = 1; off <= 8; off <<= 1)
#pragma unroll
      for (int j = 0; j < 4; ++j)
        psum[j] += __shfl_xor(psum[j], off);
#pragma unroll
    for (int j = 0; j < 4; ++j)
      lrow[j] = lrow[j] * rs_[j] + psum[j];
#pragma unroll
    for (int c = 0; c < 4; ++c)
#pragma unroll
      for (int j = 0; j < 4; ++j)
        acc[c][j] *= rs_[j];
    // P -> LDS (per-wave buffer, stride 72 elems: 2-way = free)
#pragma unroll
    for (int c = 0; c < 4; ++c)
#pragma unroll
      for (int j = 0; j < 4; ++j)
        Psh[w][(lg * 4 + j) * 72 + c * 16 + lr] = f2bf(p[c][j]);
    s8v pf0 = *(const s8v*)(&Psh[w][lr * 72 + lg * 8]);
    s8v pf1 = *(const s8v*)(&Psh[w][lr * 72 + 32 + lg * 8]);
    // O += P @ V
#pragma unroll
    for (int c = 0; c < 4; ++c) {
      int rr = c * 16 + lr;
#pragma unroll
      for (int kk = 0; kk < 2; ++kk) {
        int byte = (rr * 128 + kk * 64 + lg * 16) ^ ((rr & 7) << 4);
        s8v vf = *(const s8v*)((const char*)Vsh + byte);
        acc[c] = __builtin_amdgcn_mfma_f32_16x16x32_bf16(kk == 0 ? pf0 : pf1, vf, acc[c], 0, 0, 0);
      }
    }
    __syncthreads();
  }
  float inv[4];
#pragma unroll
  for (int j = 0; j < 4; ++j) inv[j] = 1.f / lrow[j];
  ushort_t* orow = O + ((size_t)b * TT + qt * 64 + w * 16) * DMODEL + h * 64;
#pragma unroll
  for (int c = 0; c < 4; ++c)
#pragma unroll
    for (int j = 0; j < 4; ++j)
      orow[(size_t)(lg * 4 + j) * DMODEL + c * 16 + lr] = f2bf(acc[c][j] * inv[j]);
}

// ---------------- fused residual + LayerNorm ----------------
// MODE 0: a = f32, y = bf16   |   MODE 1: a = bf16, y = f32
// y = LN(a + 2*b) * g + be
template<int MODE>
__global__ __launch_bounds__(256) void ln_kernel(const void* __restrict__ aptr,
                                                 const ushort_t* __restrict__ bptr,
                                                 const float* __restrict__ g,
                                                 const float* __restrict__ be,
                                                 void* __restrict__ yptr) {
  const int row = blockIdx.x;
  const int t = threadIdx.x;
  const int w = t >> 6, l = t & 63;
  const size_t base = (size_t)row * DMODEL + t * 4;
  float v[4];
  us4v bb = *(const us4v*)(bptr + base);
  if (MODE == 0) {
    float4 xa = *(const float4*)((const float*)aptr + base);
    v[0] = xa.x + 2.f * bf2f(bb.x);
    v[1] = xa.y + 2.f * bf2f(bb.y);
    v[2] = xa.z + 2.f * bf2f(bb.z);
    v[3] = xa.w + 2.f * bf2f(bb.w);
  } else {
    us4v xa = *(const us4v*)((const ushort_t*)aptr + base);
    v[0] = bf2f(xa.x) + 2.f * bf2f(bb.x);
    v[1] = bf2f(xa.y) + 2.f * bf2f(bb.y);
    v[2] = bf2f(xa.z) + 2.f * bf2f(bb.z);
    v[3] = bf2f(xa.w) + 2.f * bf2f(bb.w);
  }
  float s = v[0] + v[1] + v[2] + v[3];
  float s2 = v[0] * v[0] + v[1] * v[1] + v[2] * v[2] + v[3] * v[3];
#pragma unroll
  for (int off = 1; off <= 32; off <<= 1) {
    s += __shfl_xor(s, off);
    s2 += __shfl_xor(s2, off);
  }
  __shared__ float red[2][4];
  if (l == 0) { red[0][w] = s; red[1][w] = s2; }
  __syncthreads();
  s = red[0][0] + red[0][1] + red[0][2] + red[0][3];
  s2 = red[1][0] + red[1][1] + red[1][2] + red[1][3];
  const float mu = s * (1.f / 1024.f);
  const float var = s2 * (1.f / 1024.f) - mu * mu;
  const float rstd = rsqrtf(var + 1e-5f);
  float4 g4 = *(const float4*)(g + t * 4);
  float4 be4 = *(const float4*)(be + t * 4);
  float y0 = (v[0] - mu) * rstd * g4.x + be4.x;
  float y1 = (v[1] - mu) * rstd * g4.y + be4.y;
  float y2 = (v[2] - mu) * rstd * g4.z + be4.z;
  float y3 = (v[3] - mu) * rstd * g4.w + be4.w;
  if (MODE == 0) {
    us4v o;
    o.x = f2bf(y0); o.y = f2bf(y1); o.z = f2bf(y2); o.w = f2bf(y3);
    ((us4v*)yptr)[base >> 2] = o;
  } else {
    float4 o = make_float4(y0, y1, y2, y3);
    *(float4*)((float*)yptr + base) = o;
  }
}

// ---------------- launch ----------------
extern "C" void kernel_launch(void* const* d_in, const int* in_sizes, int n_in,
                              void* d_out, int out_size, void* d_ws, size_t ws_size,
                              hipStream_t stream) {
  const float* x   = (const float*)d_in[0];
  const float* Wq  = (const float*)d_in[2];
  const float* bq  = (const float*)d_in[3];
  const float* Wk  = (const float*)d_in[4];
  const float* bk  = (const float*)d_in[5];
  const float* Wv  = (const float*)d_in[6];
  const float* bv  = (const float*)d_in[7];
  const float* W1  = (const float*)d_in[8];
  const float* b1  = (const float*)d_in[9];
  const float* W2  = (const float*)d_in[10];
  const float* b2  = (const float*)d_in[11];
  const float* g1  = (const float*)d_in[12];
  const float* be1 = (const float*)d_in[13];
  const float* g2  = (const float*)d_in[14];
  const float* be2 = (const float*)d_in[15];
  float* out = (float*)d_out;

  char* ws = (char*)d_ws;
  size_t off = 0;
  auto alloc = [&](size_t bytes) {
    char* p = ws + off;
    off += (bytes + 255) & ~(size_t)255;
    return p;
  };
  ushort_t* xb    = (ushort_t*)alloc((size_t)ROWS * DMODEL * 2);
  ushort_t* WqkvT = (ushort_t*)alloc((size_t)QKVN * DMODEL * 2);
  ushort_t* W1T   = (ushort_t*)alloc((size_t)DFF * DMODEL * 2);
  ushort_t* W2T   = (ushort_t*)alloc((size_t)DMODEL * DFF * 2);
  ushort_t* QKV   = (ushort_t*)alloc((size_t)ROWS * QKVN * 2);
  ushort_t* attnb = (ushort_t*)alloc((size_t)ROWS * DMODEL * 2);
  ushort_t* x1b   = (ushort_t*)alloc((size_t)ROWS * DMODEL * 2);
  ushort_t* H1b   = (ushort_t*)alloc((size_t)ROWS * DFF * 2);
  ushort_t* ffb   = (ushort_t*)alloc((size_t)ROWS * DMODEL * 2);
  float* qkvb     = (float*)alloc(QKVN * 4);
  (void)ws_size; (void)in_sizes; (void)n_in; (void)out_size;

  dim3 b256(256);
  dim3 tb(32, 8);
  cvt_f32_bf16<<<ROWS * DMODEL / 4 / 256, b256, 0, stream>>>(x, xb, ROWS * DMODEL / 4);
  transpose_cvt<<<dim3(32, 32), tb, 0, stream>>>(Wq, WqkvT, DMODEL, DMODEL);
  transpose_cvt<<<dim3(32, 32), tb, 0, stream>>>(Wk, WqkvT + DMODEL * DMODEL, DMODEL, DMODEL);
  transpose_cvt<<<dim3(32, 32), tb, 0, stream>>>(Wv, WqkvT + 2 * DMODEL * DMODEL, DMODEL, DMODEL);
  transpose_cvt<<<dim3(DFF / 32, DMODEL / 32), tb, 0, stream>>>(W1, W1T, DMODEL, DFF);
  transpose_cvt<<<dim3(DMODEL / 32, DFF / 32), tb, 0, stream>>>(W2, W2T, DFF, DMODEL);
  concat_bias<<<4, b256, 0, stream>>>(bq, bk, bv, qkvb);

  gemm_bt<false><<<dim3(QKVN / 128, ROWS / 128), b256, 0, stream>>>(xb, WqkvT, qkvb, QKV,
                                                                    ROWS, QKVN, DMODEL);
  attn_kernel<<<dim3(TT / 64, BB * NH), b256, 0, stream>>>(QKV, attnb);
  ln_kernel<0><<<ROWS, b256, 0, stream>>>(x, attnb, g1, be1, x1b);
  gemm_bt<true><<<dim3(DFF / 128, ROWS / 128), b256, 0, stream>>>(x1b, W1T, b1, H1b,
                                                                  ROWS, DFF, DMODEL);
  gemm_bt<false><<<dim3(DMODEL / 128, ROWS / 128), b256, 0, stream>>>(H1b, W2T, b2, ffb,
                                                                      ROWS, DMODEL, DFF);
  ln_kernel<1><<<ROWS, b256, 0, stream>>>(x1b, ffb, g2, be2, out);
}

// Round 2
// 313.409 us; speedup vs baseline: 1.3277x; 1.3277x over previous
//
#include <hip/hip_runtime.h>

#define DMODEL 1024
#define DKH 64
#define NH 16
#define DFF 4096
#define BB 2
#define TT 2048
#define ROWS (BB*TT)      // 4096
#define QKVN (3*DMODEL)   // 3072

typedef unsigned short ushort_t;
typedef __attribute__((ext_vector_type(8))) short s8v;
typedef __attribute__((ext_vector_type(4))) float f4v;
typedef __attribute__((ext_vector_type(4))) unsigned short us4v;

typedef const void __attribute__((address_space(1)))* GPTR;
typedef void __attribute__((address_space(3)))* SPTR;

__device__ __forceinline__ float bf2f(ushort_t u) {
  return __uint_as_float(((unsigned int)u) << 16);
}
__device__ __forceinline__ ushort_t f2bf(float f) {
  unsigned int u = __float_as_uint(f);
  u += 0x7fffu + ((u >> 16) & 1u);
  return (ushort_t)(u >> 16);
}
__device__ __forceinline__ void gload16(const void* g, void* l) {
  __builtin_amdgcn_global_load_lds((GPTR)g, (SPTR)l, 16, 0, 0);
}

// ---------------- conversion kernels ----------------
__global__ __launch_bounds__(256) void cvt_f32_bf16(const float* __restrict__ in,
                                                    ushort_t* __restrict__ out, int n4) {
  int i = blockIdx.x * 256 + threadIdx.x;
  if (i >= n4) return;
  float4 v = ((const float4*)in)[i];
  us4v o;
  o.x = f2bf(v.x); o.y = f2bf(v.y); o.z = f2bf(v.z); o.w = f2bf(v.w);
  ((us4v*)out)[i] = o;
}

// in [R,C] f32 -> out [C,R] bf16
__global__ __launch_bounds__(256) void transpose_cvt(const float* __restrict__ in,
                                                     ushort_t* __restrict__ out, int R, int C) {
  __shared__ float tile[32][33];
  int bx = blockIdx.x * 32, by = blockIdx.y * 32;
  int tx = threadIdx.x, ty = threadIdx.y;
#pragma unroll
  for (int i = 0; i < 32; i += 8)
    tile[ty + i][tx] = in[(size_t)(by + ty + i) * C + bx + tx];
  __syncthreads();
#pragma unroll
  for (int i = 0; i < 32; i += 8)
    out[(size_t)(bx + ty + i) * R + by + tx] = f2bf(tile[tx][ty + i]);
}

__global__ void concat_bias(const float* __restrict__ a, const float* __restrict__ b,
                            const float* __restrict__ c, float* __restrict__ o) {
  int i = blockIdx.x * 256 + threadIdx.x;
  if (i < 1024) { o[i] = a[i]; o[1024 + i] = b[i]; o[2048 + i] = c[i]; }
}

// ---------------- GEMM: C[M,N] = A[M,K] @ BT[N,K]^T + bias, bf16 out ----------------
template<bool RELU>
__global__ __launch_bounds__(256) void gemm_bt(const ushort_t* __restrict__ A,
                                               const ushort_t* __restrict__ BT,
                                               const float* __restrict__ bias,
                                               ushort_t* __restrict__ C,
                                               int M, int N, int K) {
  __shared__ __align__(16) ushort_t As[128 * 32];
  __shared__ __align__(16) ushort_t Bs[128 * 32];
  const int tid = threadIdx.x;
  const int w = tid >> 6, l = tid & 63;
  const int m0 = blockIdx.y * 128, n0 = blockIdx.x * 128;
  const int wr = (w >> 1) * 64, wc = (w & 1) * 64;
  const int lr = l & 15, lg = l >> 4;
  const int srow = tid >> 2, sc8 = (tid & 3) * 8;
  f4v acc[4][4] = {};
  for (int kt = 0; kt < K; kt += 32) {
#pragma unroll
    for (int r = 0; r < 2; ++r) {
      int row = r * 64 + srow;
      gload16(A + (size_t)(m0 + row) * K + kt + sc8, (char*)As + (r * 256 + w * 64) * 16);
      gload16(BT + (size_t)(n0 + row) * K + kt + sc8, (char*)Bs + (r * 256 + w * 64) * 16);
    }
    __syncthreads();
    s8v af[4], bf[4];
#pragma unroll
    for (int m = 0; m < 4; ++m)
      af[m] = *(const s8v*)(As + (wr + m * 16 + lr) * 32 + lg * 8);
#pragma unroll
    for (int n = 0; n < 4; ++n)
      bf[n] = *(const s8v*)(Bs + (wc + n * 16 + lr) * 32 + lg * 8);
#pragma unroll
    for (int m = 0; m < 4; ++m)
#pragma unroll
      for (int n = 0; n < 4; ++n)
        acc[m][n] = __builtin_amdgcn_mfma_f32_16x16x32_bf16(af[m], bf[n], acc[m][n], 0, 0, 0);
    __syncthreads();
  }
#pragma unroll
  for (int n = 0; n < 4; ++n) {
    int col = n0 + wc + n * 16 + lr;
    float bv = bias[col];
#pragma unroll
    for (int m = 0; m < 4; ++m) {
      int row = m0 + wr + m * 16 + lg * 4;
#pragma unroll
      for (int j = 0; j < 4; ++j) {
        float v = acc[m][n][j] + bv;
        if (RELU) v = fmaxf(v, 0.f);
        C[(size_t)(row + j) * N + col] = f2bf(v);
      }
    }
  }
}

// ---------------- causal flash attention (v2) ----------------
// QKV: [ROWS, 3072] bf16 (cols: 0..1023 Q, 1024..2047 K, 2048..3071 V; col = h*64+d)
// O:   [ROWS, 1024] bf16
// Block bx handles q-tiles {bx, 31-bx} (balanced: 17 tile-computes each).
// KVBLK=128. T14 reg-staging: loads for tile kt+1 issued before compute of kt.
__global__ __launch_bounds__(256) void attn_kernel(const ushort_t* __restrict__ QKV,
                                                   ushort_t* __restrict__ O) {
  const int bx = blockIdx.x;            // 0..15
  const int bh = blockIdx.y;            // 0..31
  const int b = bh >> 4, h = bh & 15;
  const int qtLo = bx, qtHi = 31 - bx;
  const int nktLo = (bx + 2) >> 1;      // ceil((qtLo+1)*64/128)
  const int nktHi = (33 - bx) >> 1;     // ceil((qtHi+1)*64/128)
  const int tid = threadIdx.x;
  const int w = tid >> 6, l = tid & 63;
  const int lr = l & 15, lg = l >> 4;

  __shared__ __align__(16) ushort_t Ksh[128 * 64];      // [k][d], row-swizzled
  __shared__ __align__(16) ushort_t Vsh[64 * 128];      // V^T: [d][k], row-swizzled
  __shared__ __align__(16) ushort_t Psh[4][16 * 136];   // per-wave P, stride 136

  const size_t RS = QKVN;
  const ushort_t* Qb = QKV + (size_t)b * TT * RS + h * 64;
  const ushort_t* Kp = Qb + DMODEL;
  const ushort_t* Vp = Qb + 2 * DMODEL;

  // Q fragments for both q-tiles (A-frag: m=lr, k=lg*8+j (+32 per kk))
  s8v qfH[2], qfL[2];
  {
    const ushort_t* qr = Qb + (size_t)(qtHi * 64 + w * 16 + lr) * RS + lg * 8;
    qfH[0] = *(const s8v*)qr;
    qfH[1] = *(const s8v*)(qr + 32);
    qr = Qb + (size_t)(qtLo * 64 + w * 16 + lr) * RS + lg * 8;
    qfL[0] = *(const s8v*)qr;
    qfL[1] = *(const s8v*)(qr + 32);
  }
  f4v accH[4] = {}, accL[4] = {};
  float mH[4], lH[4], mL[4], lL[4];
#pragma unroll
  for (int j = 0; j < 4; ++j) {
    mH[j] = -__builtin_inff(); mL[j] = -__builtin_inff();
    lH[j] = 0.f; lL[j] = 0.f;
  }

  const int krow = tid >> 3, kcol = (tid & 7) * 8;
  s8v kreg[4];
  ushort_t vreg[32];

  auto loadKV = [&](int kt) {
#pragma unroll
    for (int s = 0; s < 4; ++s)
      kreg[s] = *(const s8v*)(Kp + (size_t)(kt * 128 + s * 32 + krow) * RS + kcol);
    // V: lane l = column d; one 128B row per wave-instruction (coalesced),
    // transpose falls out of the access shape.
#pragma unroll
    for (int i = 0; i < 32; ++i)
      vreg[i] = Vp[(size_t)(kt * 128 + w * 32 + i) * RS + l];
  };

  auto fpart = [&](int qt, int kt, bool diag, const s8v* qf, f4v* acc,
                   float* mr, float* ls) {
    float p[8][4];
#pragma unroll
    for (int c = 0; c < 8; ++c) {
      f4v a = {};
#pragma unroll
      for (int kk = 0; kk < 2; ++kk) {
        int rr = c * 16 + lr;
        int byte_ = (rr * 128 + kk * 64 + lg * 16) ^ ((rr & 7) << 4);
        s8v kf = *(const s8v*)((const char*)Ksh + byte_);
        a = __builtin_amdgcn_mfma_f32_16x16x32_bf16(qf[kk], kf, a, 0, 0, 0);
      }
#pragma unroll
      for (int j = 0; j < 4; ++j) p[c][j] = a[j] * 0.125f;
    }
    if (diag) {
#pragma unroll
      for (int c = 0; c < 8; ++c) {
        int kg = kt * 128 + c * 16 + lr;
#pragma unroll
        for (int j = 0; j < 4; ++j)
          if (kg > qt * 64 + w * 16 + lg * 4 + j) p[c][j] = -__builtin_inff();
      }
    }
    float pm[4];
#pragma unroll
    for (int j = 0; j < 4; ++j) {
      float v0 = fmaxf(fmaxf(p[0][j], p[1][j]), fmaxf(p[2][j], p[3][j]));
      float v1 = fmaxf(fmaxf(p[4][j], p[5][j]), fmaxf(p[6][j], p[7][j]));
      pm[j] = fmaxf(v0, v1);
    }
#pragma unroll
    for (int off = 1; off <= 8; off <<= 1)
#pragma unroll
      for (int j = 0; j < 4; ++j)
        pm[j] = fmaxf(pm[j], __shfl_xor(pm[j], off));
    float rs_[4];
#pragma unroll
    for (int j = 0; j < 4; ++j) {
      float mn = fmaxf(mr[j], pm[j]);
      rs_[j] = __expf(mr[j] - mn);
      mr[j] = mn;
    }
    float ps[4] = {0.f, 0.f, 0.f, 0.f};
#pragma unroll
    for (int c = 0; c < 8; ++c)
#pragma unroll
      for (int j = 0; j < 4; ++j) {
        float e = __expf(p[c][j] - mr[j]);
        p[c][j] = e;
        ps[j] += e;
      }
#pragma unroll
    for (int off = 1; off <= 8; off <<= 1)
#pragma unroll
      for (int j = 0; j < 4; ++j)
        ps[j] += __shfl_xor(ps[j], off);
#pragma unroll
    for (int j = 0; j < 4; ++j) ls[j] = ls[j] * rs_[j] + ps[j];
#pragma unroll
    for (int d = 0; d < 4; ++d)
#pragma unroll
      for (int j = 0; j < 4; ++j) acc[d][j] *= rs_[j];
    // P -> LDS (per-wave, stride 136 elems)
#pragma unroll
    for (int c = 0; c < 8; ++c)
#pragma unroll
      for (int j = 0; j < 4; ++j)
        Psh[w][(lg * 4 + j) * 136 + c * 16 + lr] = f2bf(p[c][j]);
    s8v pa[4];
#pragma unroll
    for (int ks = 0; ks < 4; ++ks)
      pa[ks] = *(const s8v*)(&Psh[w][lr * 136 + ks * 32 + lg * 8]);
    // O += P @ V  (B-frag from V^T rows)
#pragma unroll
    for (int ks = 0; ks < 4; ++ks)
#pragma unroll
      for (int d = 0; d < 4; ++d) {
        int row = d * 16 + lr;
        int byte_ = (row * 256 + ks * 64 + lg * 16) ^ ((row & 7) << 4);
        s8v vf = *(const s8v*)((const char*)Vsh + byte_);
        acc[d] = __builtin_amdgcn_mfma_f32_16x16x32_bf16(pa[ks], vf, acc[d], 0, 0, 0);
      }
  };

  loadKV(0);
  for (int kt = 0; kt < nktHi; ++kt) {
    __syncthreads();   // prev-iter LDS consumers done
    // write staged regs -> LDS
#pragma unroll
    for (int s = 0; s < 4; ++s) {
      int r = s * 32 + krow;
      int byte_ = (r * 128 + kcol * 2) ^ ((r & 7) << 4);
      *(s8v*)((char*)Ksh + byte_) = kreg[s];
    }
#pragma unroll
    for (int ch = 0; ch < 4; ++ch) {
      s8v pv;
#pragma unroll
      for (int j = 0; j < 8; ++j) pv[j] = (short)vreg[ch * 8 + j];
      int byte_ = (l * 256 + w * 64 + ch * 16) ^ ((l & 7) << 4);
      *(s8v*)((char*)Vsh + byte_) = pv;
    }
    __syncthreads();
    if (kt + 1 < nktHi) loadKV(kt + 1);  // prefetch next tile (hides under compute)
    fpart(qtHi, kt, kt == nktHi - 1, qfH, accH, mH, lH);
    if (kt < nktLo) fpart(qtLo, kt, kt == nktLo - 1, qfL, accL, mL, lL);
  }

  // epilogue: normalize + store both q-tiles
  {
    float inv[4];
#pragma unroll
    for (int j = 0; j < 4; ++j) inv[j] = 1.f / lH[j];
    ushort_t* orow = O + ((size_t)b * TT + qtHi * 64 + w * 16) * DMODEL + h * 64;
#pragma unroll
    for (int d = 0; d < 4; ++d)
#pragma unroll
      for (int j = 0; j < 4; ++j)
        orow[(size_t)(lg * 4 + j) * DMODEL + d * 16 + lr] = f2bf(accH[d][j] * inv[j]);
#pragma unroll
    for (int j = 0; j < 4; ++j) inv[j] = 1.f / lL[j];
    orow = O + ((size_t)b * TT + qtLo * 64 + w * 16) * DMODEL + h * 64;
#pragma unroll
    for (int d = 0; d < 4; ++d)
#pragma unroll
      for (int j = 0; j < 4; ++j)
        orow[(size_t)(lg * 4 + j) * DMODEL + d * 16 + lr] = f2bf(accL[d][j] * inv[j]);
  }
}

// ---------------- fused residual + LayerNorm ----------------
// MODE 0: a = f32, y = bf16   |   MODE 1: a = bf16, y = f32
// y = LN(a + 2*b) * g + be
template<int MODE>
__global__ __launch_bounds__(256) void ln_kernel(const void* __restrict__ aptr,
                                                 const ushort_t* __restrict__ bptr,
                                                 const float* __restrict__ g,
                                                 const float* __restrict__ be,
                                                 void* __restrict__ yptr) {
  const int row = blockIdx.x;
  const int t = threadIdx.x;
  const int w = t >> 6, l = t & 63;
  const size_t base = (size_t)row * DMODEL + t * 4;
  float v[4];
  us4v bb = *(const us4v*)(bptr + base);
  if (MODE == 0) {
    float4 xa = *(const float4*)((const float*)aptr + base);
    v[0] = xa.x + 2.f * bf2f(bb.x);
    v[1] = xa.y + 2.f * bf2f(bb.y);
    v[2] = xa.z + 2.f * bf2f(bb.z);
    v[3] = xa.w + 2.f * bf2f(bb.w);
  } else {
    us4v xa = *(const us4v*)((const ushort_t*)aptr + base);
    v[0] = bf2f(xa.x) + 2.f * bf2f(bb.x);
    v[1] = bf2f(xa.y) + 2.f * bf2f(bb.y);
    v[2] = bf2f(xa.z) + 2.f * bf2f(bb.z);
    v[3] = bf2f(xa.w) + 2.f * bf2f(bb.w);
  }
  float s = v[0] + v[1] + v[2] + v[3];
  float s2 = v[0] * v[0] + v[1] * v[1] + v[2] * v[2] + v[3] * v[3];
#pragma unroll
  for (int off = 1; off <= 32; off <<= 1) {
    s += __shfl_xor(s, off);
    s2 += __shfl_xor(s2, off);
  }
  __shared__ float red[2][4];
  if (l == 0) { red[0][w] = s; red[1][w] = s2; }
  __syncthreads();
  s = red[0][0] + red[0][1] + red[0][2] + red[0][3];
  s2 = red[1][0] + red[1][1] + red[1][2] + red[1][3];
  const float mu = s * (1.f / 1024.f);
  const float var = s2 * (1.f / 1024.f) - mu * mu;
  const float rstd = rsqrtf(var + 1e-5f);
  float4 g4 = *(const float4*)(g + t * 4);
  float4 be4 = *(const float4*)(be + t * 4);
  float y0 = (v[0] - mu) * rstd * g4.x + be4.x;
  float y1 = (v[1] - mu) * rstd * g4.y + be4.y;
  float y2 = (v[2] - mu) * rstd * g4.z + be4.z;
  float y3 = (v[3] - mu) * rstd * g4.w + be4.w;
  if (MODE == 0) {
    us4v o;
    o.x = f2bf(y0); o.y = f2bf(y1); o.z = f2bf(y2); o.w = f2bf(y3);
    ((us4v*)yptr)[base >> 2] = o;
  } else {
    float4 o = make_float4(y0, y1, y2, y3);
    *(float4*)((float*)yptr + base) = o;
  }
}

// ---------------- launch ----------------
extern "C" void kernel_launch(void* const* d_in, const int* in_sizes, int n_in,
                              void* d_out, int out_size, void* d_ws, size_t ws_size,
                              hipStream_t stream) {
  const float* x   = (const float*)d_in[0];
  const float* Wq  = (const float*)d_in[2];
  const float* bq  = (const float*)d_in[3];
  const float* Wk  = (const float*)d_in[4];
  const float* bk  = (const float*)d_in[5];
  const float* Wv  = (const float*)d_in[6];
  const float* bv  = (const float*)d_in[7];
  const float* W1  = (const float*)d_in[8];
  const float* b1  = (const float*)d_in[9];
  const float* W2  = (const float*)d_in[10];
  const float* b2  = (const float*)d_in[11];
  const float* g1  = (const float*)d_in[12];
  const float* be1 = (const float*)d_in[13];
  const float* g2  = (const float*)d_in[14];
  const float* be2 = (const float*)d_in[15];
  float* out = (float*)d_out;

  char* ws = (char*)d_ws;
  size_t off = 0;
  auto alloc = [&](size_t bytes) {
    char* p = ws + off;
    off += (bytes + 255) & ~(size_t)255;
    return p;
  };
  ushort_t* xb    = (ushort_t*)alloc((size_t)ROWS * DMODEL * 2);
  ushort_t* WqkvT = (ushort_t*)alloc((size_t)QKVN * DMODEL * 2);
  ushort_t* W1T   = (ushort_t*)alloc((size_t)DFF * DMODEL * 2);
  ushort_t* W2T   = (ushort_t*)alloc((size_t)DMODEL * DFF * 2);
  ushort_t* QKV   = (ushort_t*)alloc((size_t)ROWS * QKVN * 2);
  ushort_t* attnb = (ushort_t*)alloc((size_t)ROWS * DMODEL * 2);
  ushort_t* x1b   = (ushort_t*)alloc((size_t)ROWS * DMODEL * 2);
  ushort_t* H1b   = (ushort_t*)alloc((size_t)ROWS * DFF * 2);
  ushort_t* ffb   = (ushort_t*)alloc((size_t)ROWS * DMODEL * 2);
  float* qkvb     = (float*)alloc(QKVN * 4);
  (void)ws_size; (void)in_sizes; (void)n_in; (void)out_size;

  dim3 b256(256);
  dim3 tb(32, 8);
  cvt_f32_bf16<<<ROWS * DMODEL / 4 / 256, b256, 0, stream>>>(x, xb, ROWS * DMODEL / 4);
  transpose_cvt<<<dim3(32, 32), tb, 0, stream>>>(Wq, WqkvT, DMODEL, DMODEL);
  transpose_cvt<<<dim3(32, 32), tb, 0, stream>>>(Wk, WqkvT + DMODEL * DMODEL, DMODEL, DMODEL);
  transpose_cvt<<<dim3(32, 32), tb, 0, stream>>>(Wv, WqkvT + 2 * DMODEL * DMODEL, DMODEL, DMODEL);
  transpose_cvt<<<dim3(DFF / 32, DMODEL / 32), tb, 0, stream>>>(W1, W1T, DMODEL, DFF);
  transpose_cvt<<<dim3(DMODEL / 32, DFF / 32), tb, 0, stream>>>(W2, W2T, DFF, DMODEL);
  concat_bias<<<4, b256, 0, stream>>>(bq, bk, bv, qkvb);

  gemm_bt<false><<<dim3(QKVN / 128, ROWS / 128), b256, 0, stream>>>(xb, WqkvT, qkvb, QKV,
                                                                    ROWS, QKVN, DMODEL);
  attn_kernel<<<dim3(16, BB * NH), b256, 0, stream>>>(QKV, attnb);
  ln_kernel<0><<<ROWS, b256, 0, stream>>>(x, attnb, g1, be1, x1b);
  gemm_bt<true><<<dim3(DFF / 128, ROWS / 128), b256, 0, stream>>>(x1b, W1T, b1, H1b,
                                                                  ROWS, DFF, DMODEL);
  gemm_bt<false><<<dim3(DMODEL / 128, ROWS / 128), b256, 0, stream>>>(H1b, W2T, b2, ffb,
                                                                      ROWS, DMODEL, DFF);
  ln_kernel<1><<<ROWS, b256, 0, stream>>>(x1b, ffb, g2, be2, out);
}

// Round 3
// 309.349 us; speedup vs baseline: 1.3451x; 1.0131x over previous
//
#include <hip/hip_runtime.h>

#define DMODEL 1024
#define DKH 64
#define NH 16
#define DFF 4096
#define BB 2
#define TT 2048
#define ROWS (BB*TT)      // 4096
#define QKVN (3*DMODEL)   // 3072

typedef unsigned short ushort_t;
typedef __attribute__((ext_vector_type(8))) short s8v;
typedef __attribute__((ext_vector_type(4))) float f4v;
typedef __attribute__((ext_vector_type(4))) unsigned short us4v;

typedef const void __attribute__((address_space(1)))* GPTR;
typedef void __attribute__((address_space(3)))* SPTR;

__device__ __forceinline__ float bf2f(ushort_t u) {
  return __uint_as_float(((unsigned int)u) << 16);
}
__device__ __forceinline__ ushort_t f2bf(float f) {
  unsigned int u = __float_as_uint(f);
  u += 0x7fffu + ((u >> 16) & 1u);
  return (ushort_t)(u >> 16);
}
__device__ __forceinline__ void gload16(const void* g, void* l) {
  __builtin_amdgcn_global_load_lds((GPTR)g, (SPTR)l, 16, 0, 0);
}

// ---------------- conversion kernels ----------------
__global__ __launch_bounds__(256) void cvt_f32_bf16(const float* __restrict__ in,
                                                    ushort_t* __restrict__ out, int n4) {
  int i = blockIdx.x * 256 + threadIdx.x;
  if (i >= n4) return;
  float4 v = ((const float4*)in)[i];
  us4v o;
  o.x = f2bf(v.x); o.y = f2bf(v.y); o.z = f2bf(v.z); o.w = f2bf(v.w);
  ((us4v*)out)[i] = o;
}

// in [R,C] f32 -> out [C,R] bf16
__global__ __launch_bounds__(256) void transpose_cvt(const float* __restrict__ in,
                                                     ushort_t* __restrict__ out, int R, int C) {
  __shared__ float tile[32][33];
  int bx = blockIdx.x * 32, by = blockIdx.y * 32;
  int tx = threadIdx.x, ty = threadIdx.y;
#pragma unroll
  for (int i = 0; i < 32; i += 8)
    tile[ty + i][tx] = in[(size_t)(by + ty + i) * C + bx + tx];
  __syncthreads();
#pragma unroll
  for (int i = 0; i < 32; i += 8)
    out[(size_t)(bx + ty + i) * R + by + tx] = f2bf(tile[tx][ty + i]);
}

__global__ void concat_bias(const float* __restrict__ a, const float* __restrict__ b,
                            const float* __restrict__ c, float* __restrict__ o) {
  int i = blockIdx.x * 256 + threadIdx.x;
  if (i < 1024) { o[i] = a[i]; o[1024 + i] = b[i]; o[2048 + i] = c[i]; }
}

// ---------------- GEMM 128^2 (m97 structure), used for FFN2 ----------------
template<bool RELU>
__global__ __launch_bounds__(256) void gemm_bt(const ushort_t* __restrict__ A,
                                               const ushort_t* __restrict__ BT,
                                               const float* __restrict__ bias,
                                               ushort_t* __restrict__ C,
                                               int M, int N, int K) {
  __shared__ __align__(16) ushort_t As[128 * 32];
  __shared__ __align__(16) ushort_t Bs[128 * 32];
  const int tid = threadIdx.x;
  const int w = tid >> 6, l = tid & 63;
  const int m0 = blockIdx.y * 128, n0 = blockIdx.x * 128;
  const int wr = (w >> 1) * 64, wc = (w & 1) * 64;
  const int lr = l & 15, lg = l >> 4;
  const int srow = tid >> 2, sc8 = (tid & 3) * 8;
  f4v acc[4][4] = {};
  for (int kt = 0; kt < K; kt += 32) {
#pragma unroll
    for (int r = 0; r < 2; ++r) {
      int row = r * 64 + srow;
      gload16(A + (size_t)(m0 + row) * K + kt + sc8, (char*)As + (r * 256 + w * 64) * 16);
      gload16(BT + (size_t)(n0 + row) * K + kt + sc8, (char*)Bs + (r * 256 + w * 64) * 16);
    }
    __syncthreads();
    s8v af[4], bf[4];
#pragma unroll
    for (int m = 0; m < 4; ++m)
      af[m] = *(const s8v*)(As + (wr + m * 16 + lr) * 32 + lg * 8);
#pragma unroll
    for (int n = 0; n < 4; ++n)
      bf[n] = *(const s8v*)(Bs + (wc + n * 16 + lr) * 32 + lg * 8);
#pragma unroll
    for (int m = 0; m < 4; ++m)
#pragma unroll
      for (int n = 0; n < 4; ++n)
        acc[m][n] = __builtin_amdgcn_mfma_f32_16x16x32_bf16(af[m], bf[n], acc[m][n], 0, 0, 0);
    __syncthreads();
  }
#pragma unroll
  for (int n = 0; n < 4; ++n) {
    int col = n0 + wc + n * 16 + lr;
    float bv = bias[col];
#pragma unroll
    for (int m = 0; m < 4; ++m) {
      int row = m0 + wr + m * 16 + lg * 4;
#pragma unroll
      for (int j = 0; j < 4; ++j) {
        float v = acc[m][n][j] + bv;
        if (RELU) v = fmaxf(v, 0.f);
        C[(size_t)(row + j) * N + col] = f2bf(v);
      }
    }
  }
}

// ---------------- GEMM 256^2 8-phase (T2+T3+T4+T5), QKV & FFN1 ----------------
// C[M,N] = A[M,K] @ BT[N,K]^T + bias.  512 thr = 8 waves (2M x 4N), BK=64.
// LDS: 2 dbuf x {A[2][128][64], B[2][128][64]} bf16 = 128 KiB.
// st_16x32 swizzle: byte ^= ((byte>>9)&1)<<5  (inverse-swz source, swz read).
// Stage schedule (group t computes tile t from buf[t&1]):
//   P1: stage (t+1).B0 -> buf[(t+1)&1]   (buffer not read this group)
//   P2: stage (t+1).B1 -> buf[(t+1)&1]
//   P3: stage (t+2).A0 -> buf[t&1]       (A0 reads completed by P2-end barrier)
//   P4: stage (t+2).A1 -> buf[t&1]
// Group end: vmcnt(4) (2 half-tiles in flight) -- never 0 mid-loop.
template<bool RELU>
__global__ __launch_bounds__(512, 2) void gemm256(const ushort_t* __restrict__ A,
                                                  const ushort_t* __restrict__ BT,
                                                  const float* __restrict__ bias,
                                                  ushort_t* __restrict__ C,
                                                  int M, int N, int K, int nbx) {
  __shared__ __align__(16) ushort_t Abuf[2][2][128 * 64];
  __shared__ __align__(16) ushort_t Bbuf[2][2][128 * 64];
  const int nwg = gridDim.x;
  const int wg = blockIdx.x;
  const int cpx = nwg >> 3;                       // nwg % 8 == 0 (launcher guarantees)
  const int swz = (wg & 7) * cpx + (wg >> 3);     // XCD-aware swizzle (T1)
  const int bx = swz % nbx, by = swz / nbx;
  const int m0 = by * 256, n0 = bx * 256;
  const int tid = threadIdx.x;
  const int w = tid >> 6, l = tid & 63, lr = l & 15, lg = l >> 4;
  const int wm = w >> 2, wn = w & 3;

  // staging source decode (pre-swizzled global address, linear LDS dest)
  const int Ls = (tid * 16) ^ (((tid >> 5) & 1) << 5);
  const int srow = Ls >> 7;          // 0..63 (+64 for r=1)
  const int scol = (Ls & 127) >> 1;  // element col 0..63, multiple of 8

  auto stageA = [&](int kt, int half, int buf) {
    const ushort_t* gp = A + (size_t)(m0 + half * 128 + srow) * K + kt * 64 + scol;
    char* lp = (char*)&Abuf[buf][half][0] + w * 1024;
    gload16(gp, lp);
    gload16(gp + (size_t)64 * K, lp + 8192);
  };
  auto stageB = [&](int kt, int half, int buf) {
    const ushort_t* gp = BT + (size_t)(n0 + half * 128 + srow) * K + kt * 64 + scol;
    char* lp = (char*)&Bbuf[buf][half][0] + w * 1024;
    gload16(gp, lp);
    gload16(gp + (size_t)64 * K, lp + 8192);
  };

  const int acol = lg * 16 ^ (((lr >> 2) & 1) << 5);  // swizzled col-byte
  auto ldA = [&](int buf, int m, int kk) -> s8v {
    return *(const s8v*)((const char*)&Abuf[buf][wm][0] + (m * 16 + lr) * 128 + kk * 64 + acol);
  };
  auto ldB = [&](int buf, int n, int kk) -> s8v {
    return *(const s8v*)((const char*)&Bbuf[buf][wn >> 1][0] +
                         ((wn & 1) * 64 + n * 16 + lr) * 128 + kk * 64 + acol);
  };

  f4v acc[8][4] = {};
  const int NT = K >> 6;

  // prologue: tile0 full -> buf0; tile1 A halves -> buf1
  stageA(0, 0, 0); stageA(0, 1, 0); stageB(0, 0, 0); stageB(0, 1, 0);
  stageA(1, 0, 1); stageA(1, 1, 1);
  asm volatile("s_waitcnt vmcnt(4)" ::: "memory");
  __builtin_amdgcn_sched_barrier(0);
  __builtin_amdgcn_s_barrier();

  for (int t = 0; t < NT; ++t) {
    const int cb = t & 1, nb = cb ^ 1;
    s8v af[2][4], af2[2][4], bf[2][4];
    // ---- P1: read af(m0-3) + bf(all); stage (t+1).B0; MFMA m0-3 x n0-1
#pragma unroll
    for (int m = 0; m < 4; ++m) { af[0][m] = ldA(cb, m, 0); af[1][m] = ldA(cb, m, 1); }
#pragma unroll
    for (int n = 0; n < 4; ++n) { bf[0][n] = ldB(cb, n, 0); bf[1][n] = ldB(cb, n, 1); }
    if (t + 1 < NT) stageB(t + 1, 0, nb);
    __builtin_amdgcn_s_barrier();
    asm volatile("s_waitcnt lgkmcnt(0)" ::: "memory");
    __builtin_amdgcn_s_setprio(1);
#pragma unroll
    for (int m = 0; m < 4; ++m)
#pragma unroll
      for (int n = 0; n < 2; ++n) {
        acc[m][n] = __builtin_amdgcn_mfma_f32_16x16x32_bf16(af[0][m], bf[0][n], acc[m][n], 0, 0, 0);
        acc[m][n] = __builtin_amdgcn_mfma_f32_16x16x32_bf16(af[1][m], bf[1][n], acc[m][n], 0, 0, 0);
      }
    __builtin_amdgcn_s_setprio(0);
    __builtin_amdgcn_s_barrier();
    // ---- P2: read af2(m4-7); stage (t+1).B1; MFMA m0-3 x n2-3
#pragma unroll
    for (int m = 0; m < 4; ++m) { af2[0][m] = ldA(cb, 4 + m, 0); af2[1][m] = ldA(cb, 4 + m, 1); }
    if (t + 1 < NT) stageB(t + 1, 1, nb);
    __builtin_amdgcn_s_barrier();
    asm volatile("s_waitcnt lgkmcnt(0)" ::: "memory");
    __builtin_amdgcn_s_setprio(1);
#pragma unroll
    for (int m = 0; m < 4; ++m)
#pragma unroll
      for (int n = 2; n < 4; ++n) {
        acc[m][n] = __builtin_amdgcn_mfma_f32_16x16x32_bf16(af[0][m], bf[0][n], acc[m][n], 0, 0, 0);
        acc[m][n] = __builtin_amdgcn_mfma_f32_16x16x32_bf16(af[1][m], bf[1][n], acc[m][n], 0, 0, 0);
      }
    __builtin_amdgcn_s_setprio(0);
    __builtin_amdgcn_s_barrier();
    // ---- P3: stage (t+2).A0 (reads of A done); MFMA m4-7 x n0-1
    if (t + 2 < NT) stageA(t + 2, 0, cb);
    __builtin_amdgcn_s_barrier();
    asm volatile("s_waitcnt lgkmcnt(0)" ::: "memory");
    __builtin_amdgcn_s_setprio(1);
#pragma unroll
    for (int m = 0; m < 4; ++m)
#pragma unroll
      for (int n = 0; n < 2; ++n) {
        acc[4 + m][n] = __builtin_amdgcn_mfma_f32_16x16x32_bf16(af2[0][m], bf[0][n], acc[4 + m][n], 0, 0, 0);
        acc[4 + m][n] = __builtin_amdgcn_mfma_f32_16x16x32_bf16(af2[1][m], bf[1][n], acc[4 + m][n], 0, 0, 0);
      }
    __builtin_amdgcn_s_setprio(0);
    __builtin_amdgcn_s_barrier();
    // ---- P4: stage (t+2).A1; MFMA m4-7 x n2-3; counted vmcnt at group end
    if (t + 2 < NT) stageA(t + 2, 1, cb);
    __builtin_amdgcn_s_barrier();
    asm volatile("s_waitcnt lgkmcnt(0)" ::: "memory");
    __builtin_amdgcn_s_setprio(1);
#pragma unroll
    for (int m = 0; m < 4; ++m)
#pragma unroll
      for (int n = 2; n < 4; ++n) {
        acc[4 + m][n] = __builtin_amdgcn_mfma_f32_16x16x32_bf16(af2[0][m], bf[0][n], acc[4 + m][n], 0, 0, 0);
        acc[4 + m][n] = __builtin_amdgcn_mfma_f32_16x16x32_bf16(af2[1][m], bf[1][n], acc[4 + m][n], 0, 0, 0);
      }
    __builtin_amdgcn_s_setprio(0);
    if (t + 2 < NT) {
      asm volatile("s_waitcnt vmcnt(4)" ::: "memory");
    } else if (t + 1 < NT) {
      asm volatile("s_waitcnt vmcnt(0)" ::: "memory");
    }
    __builtin_amdgcn_sched_barrier(0);
    __builtin_amdgcn_s_barrier();
  }

  // epilogue
#pragma unroll
  for (int n = 0; n < 4; ++n) {
    int col = n0 + wn * 64 + n * 16 + lr;
    float bv = bias[col];
#pragma unroll
    for (int m = 0; m < 8; ++m) {
      int row = m0 + wm * 128 + m * 16 + lg * 4;
#pragma unroll
      for (int j = 0; j < 4; ++j) {
        float v = acc[m][n][j] + bv;
        if (RELU) v = fmaxf(v, 0.f);
        C[(size_t)(row + j) * N + col] = f2bf(v);
      }
    }
  }
}

// ---------------- causal flash attention (v2) ----------------
__global__ __launch_bounds__(256) void attn_kernel(const ushort_t* __restrict__ QKV,
                                                   ushort_t* __restrict__ O) {
  const int bx = blockIdx.x;            // 0..15
  const int bh = blockIdx.y;            // 0..31
  const int b = bh >> 4, h = bh & 15;
  const int qtLo = bx, qtHi = 31 - bx;
  const int nktLo = (bx + 2) >> 1;
  const int nktHi = (33 - bx) >> 1;
  const int tid = threadIdx.x;
  const int w = tid >> 6, l = tid & 63;
  const int lr = l & 15, lg = l >> 4;

  __shared__ __align__(16) ushort_t Ksh[128 * 64];
  __shared__ __align__(16) ushort_t Vsh[64 * 128];
  __shared__ __align__(16) ushort_t Psh[4][16 * 136];

  const size_t RS = QKVN;
  const ushort_t* Qb = QKV + (size_t)b * TT * RS + h * 64;
  const ushort_t* Kp = Qb + DMODEL;
  const ushort_t* Vp = Qb + 2 * DMODEL;

  s8v qfH[2], qfL[2];
  {
    const ushort_t* qr = Qb + (size_t)(qtHi * 64 + w * 16 + lr) * RS + lg * 8;
    qfH[0] = *(const s8v*)qr;
    qfH[1] = *(const s8v*)(qr + 32);
    qr = Qb + (size_t)(qtLo * 64 + w * 16 + lr) * RS + lg * 8;
    qfL[0] = *(const s8v*)qr;
    qfL[1] = *(const s8v*)(qr + 32);
  }
  f4v accH[4] = {}, accL[4] = {};
  float mH[4], lH[4], mL[4], lL[4];
#pragma unroll
  for (int j = 0; j < 4; ++j) {
    mH[j] = -__builtin_inff(); mL[j] = -__builtin_inff();
    lH[j] = 0.f; lL[j] = 0.f;
  }

  const int krow = tid >> 3, kcol = (tid & 7) * 8;
  s8v kreg[4];
  ushort_t vreg[32];

  auto loadKV = [&](int kt) {
#pragma unroll
    for (int s = 0; s < 4; ++s)
      kreg[s] = *(const s8v*)(Kp + (size_t)(kt * 128 + s * 32 + krow) * RS + kcol);
#pragma unroll
    for (int i = 0; i < 32; ++i)
      vreg[i] = Vp[(size_t)(kt * 128 + w * 32 + i) * RS + l];
  };

  auto fpart = [&](int qt, int kt, bool diag, const s8v* qf, f4v* acc,
                   float* mr, float* ls) {
    float p[8][4];
#pragma unroll
    for (int c = 0; c < 8; ++c) {
      f4v a = {};
#pragma unroll
      for (int kk = 0; kk < 2; ++kk) {
        int rr = c * 16 + lr;
        int byte_ = (rr * 128 + kk * 64 + lg * 16) ^ ((rr & 7) << 4);
        s8v kf = *(const s8v*)((const char*)Ksh + byte_);
        a = __builtin_amdgcn_mfma_f32_16x16x32_bf16(qf[kk], kf, a, 0, 0, 0);
      }
#pragma unroll
      for (int j = 0; j < 4; ++j) p[c][j] = a[j] * 0.125f;
    }
    if (diag) {
#pragma unroll
      for (int c = 0; c < 8; ++c) {
        int kg = kt * 128 + c * 16 + lr;
#pragma unroll
        for (int j = 0; j < 4; ++j)
          if (kg > qt * 64 + w * 16 + lg * 4 + j) p[c][j] = -__builtin_inff();
      }
    }
    float pm[4];
#pragma unroll
    for (int j = 0; j < 4; ++j) {
      float v0 = fmaxf(fmaxf(p[0][j], p[1][j]), fmaxf(p[2][j], p[3][j]));
      float v1 = fmaxf(fmaxf(p[4][j], p[5][j]), fmaxf(p[6][j], p[7][j]));
      pm[j] = fmaxf(v0, v1);
    }
#pragma unroll
    for (int off = 1; off <= 8; off <<= 1)
#pragma unroll
      for (int j = 0; j < 4; ++j)
        pm[j] = fmaxf(pm[j], __shfl_xor(pm[j], off));
    float rs_[4];
#pragma unroll
    for (int j = 0; j < 4; ++j) {
      float mn = fmaxf(mr[j], pm[j]);
      rs_[j] = __expf(mr[j] - mn);
      mr[j] = mn;
    }
    float ps[4] = {0.f, 0.f, 0.f, 0.f};
#pragma unroll
    for (int c = 0; c < 8; ++c)
#pragma unroll
      for (int j = 0; j < 4; ++j) {
        float e = __expf(p[c][j] - mr[j]);
        p[c][j] = e;
        ps[j] += e;
      }
#pragma unroll
    for (int off = 1; off <= 8; off <<= 1)
#pragma unroll
      for (int j = 0; j < 4; ++j)
        ps[j] += __shfl_xor(ps[j], off);
#pragma unroll
    for (int j = 0; j < 4; ++j) ls[j] = ls[j] * rs_[j] + ps[j];
#pragma unroll
    for (int d = 0; d < 4; ++d)
#pragma unroll
      for (int j = 0; j < 4; ++j) acc[d][j] *= rs_[j];
#pragma unroll
    for (int c = 0; c < 8; ++c)
#pragma unroll
      for (int j = 0; j < 4; ++j)
        Psh[w][(lg * 4 + j) * 136 + c * 16 + lr] = f2bf(p[c][j]);
    s8v pa[4];
#pragma unroll
    for (int ks = 0; ks < 4; ++ks)
      pa[ks] = *(const s8v*)(&Psh[w][lr * 136 + ks * 32 + lg * 8]);
#pragma unroll
    for (int ks = 0; ks < 4; ++ks)
#pragma unroll
      for (int d = 0; d < 4; ++d) {
        int row = d * 16 + lr;
        int byte_ = (row * 256 + ks * 64 + lg * 16) ^ ((row & 7) << 4);
        s8v vf = *(const s8v*)((const char*)Vsh + byte_);
        acc[d] = __builtin_amdgcn_mfma_f32_16x16x32_bf16(pa[ks], vf, acc[d], 0, 0, 0);
      }
  };

  loadKV(0);
  for (int kt = 0; kt < nktHi; ++kt) {
    __syncthreads();
#pragma unroll
    for (int s = 0; s < 4; ++s) {
      int r = s * 32 + krow;
      int byte_ = (r * 128 + kcol * 2) ^ ((r & 7) << 4);
      *(s8v*)((char*)Ksh + byte_) = kreg[s];
    }
#pragma unroll
    for (int ch = 0; ch < 4; ++ch) {
      s8v pv;
#pragma unroll
      for (int j = 0; j < 8; ++j) pv[j] = (short)vreg[ch * 8 + j];
      int byte_ = (l * 256 + w * 64 + ch * 16) ^ ((l & 7) << 4);
      *(s8v*)((char*)Vsh + byte_) = pv;
    }
    __syncthreads();
    if (kt + 1 < nktHi) loadKV(kt + 1);
    fpart(qtHi, kt, kt == nktHi - 1, qfH, accH, mH, lH);
    if (kt < nktLo) fpart(qtLo, kt, kt == nktLo - 1, qfL, accL, mL, lL);
  }

  {
    float inv[4];
#pragma unroll
    for (int j = 0; j < 4; ++j) inv[j] = 1.f / lH[j];
    ushort_t* orow = O + ((size_t)b * TT + qtHi * 64 + w * 16) * DMODEL + h * 64;
#pragma unroll
    for (int d = 0; d < 4; ++d)
#pragma unroll
      for (int j = 0; j < 4; ++j)
        orow[(size_t)(lg * 4 + j) * DMODEL + d * 16 + lr] = f2bf(accH[d][j] * inv[j]);
#pragma unroll
    for (int j = 0; j < 4; ++j) inv[j] = 1.f / lL[j];
    orow = O + ((size_t)b * TT + qtLo * 64 + w * 16) * DMODEL + h * 64;
#pragma unroll
    for (int d = 0; d < 4; ++d)
#pragma unroll
      for (int j = 0; j < 4; ++j)
        orow[(size_t)(lg * 4 + j) * DMODEL + d * 16 + lr] = f2bf(accL[d][j] * inv[j]);
  }
}

// ---------------- fused residual + LayerNorm ----------------
template<int MODE>
__global__ __launch_bounds__(256) void ln_kernel(const void* __restrict__ aptr,
                                                 const ushort_t* __restrict__ bptr,
                                                 const float* __restrict__ g,
                                                 const float* __restrict__ be,
                                                 void* __restrict__ yptr) {
  const int row = blockIdx.x;
  const int t = threadIdx.x;
  const int w = t >> 6, l = t & 63;
  const size_t base = (size_t)row * DMODEL + t * 4;
  float v[4];
  us4v bb = *(const us4v*)(bptr + base);
  if (MODE == 0) {
    float4 xa = *(const float4*)((const float*)aptr + base);
    v[0] = xa.x + 2.f * bf2f(bb.x);
    v[1] = xa.y + 2.f * bf2f(bb.y);
    v[2] = xa.z + 2.f * bf2f(bb.z);
    v[3] = xa.w + 2.f * bf2f(bb.w);
  } else {
    us4v xa = *(const us4v*)((const ushort_t*)aptr + base);
    v[0] = bf2f(xa.x) + 2.f * bf2f(bb.x);
    v[1] = bf2f(xa.y) + 2.f * bf2f(bb.y);
    v[2] = bf2f(xa.z) + 2.f * bf2f(bb.z);
    v[3] = bf2f(xa.w) + 2.f * bf2f(bb.w);
  }
  float s = v[0] + v[1] + v[2] + v[3];
  float s2 = v[0] * v[0] + v[1] * v[1] + v[2] * v[2] + v[3] * v[3];
#pragma unroll
  for (int off = 1; off <= 32; off <<= 1) {
    s += __shfl_xor(s, off);
    s2 += __shfl_xor(s2, off);
  }
  __shared__ float red[2][4];
  if (l == 0) { red[0][w] = s; red[1][w] = s2; }
  __syncthreads();
  s = red[0][0] + red[0][1] + red[0][2] + red[0][3];
  s2 = red[1][0] + red[1][1] + red[1][2] + red[1][3];
  const float mu = s * (1.f / 1024.f);
  const float var = s2 * (1.f / 1024.f) - mu * mu;
  const float rstd = rsqrtf(var + 1e-5f);
  float4 g4 = *(const float4*)(g + t * 4);
  float4 be4 = *(const float4*)(be + t * 4);
  float y0 = (v[0] - mu) * rstd * g4.x + be4.x;
  float y1 = (v[1] - mu) * rstd * g4.y + be4.y;
  float y2 = (v[2] - mu) * rstd * g4.z + be4.z;
  float y3 = (v[3] - mu) * rstd * g4.w + be4.w;
  if (MODE == 0) {
    us4v o;
    o.x = f2bf(y0); o.y = f2bf(y1); o.z = f2bf(y2); o.w = f2bf(y3);
    ((us4v*)yptr)[base >> 2] = o;
  } else {
    float4 o = make_float4(y0, y1, y2, y3);
    *(float4*)((float*)yptr + base) = o;
  }
}

// ---------------- launch ----------------
extern "C" void kernel_launch(void* const* d_in, const int* in_sizes, int n_in,
                              void* d_out, int out_size, void* d_ws, size_t ws_size,
                              hipStream_t stream) {
  const float* x   = (const float*)d_in[0];
  const float* Wq  = (const float*)d_in[2];
  const float* bq  = (const float*)d_in[3];
  const float* Wk  = (const float*)d_in[4];
  const float* bk  = (const float*)d_in[5];
  const float* Wv  = (const float*)d_in[6];
  const float* bv  = (const float*)d_in[7];
  const float* W1  = (const float*)d_in[8];
  const float* b1  = (const float*)d_in[9];
  const float* W2  = (const float*)d_in[10];
  const float* b2  = (const float*)d_in[11];
  const float* g1  = (const float*)d_in[12];
  const float* be1 = (const float*)d_in[13];
  const float* g2  = (const float*)d_in[14];
  const float* be2 = (const float*)d_in[15];
  float* out = (float*)d_out;

  char* ws = (char*)d_ws;
  size_t off = 0;
  auto alloc = [&](size_t bytes) {
    char* p = ws + off;
    off += (bytes + 255) & ~(size_t)255;
    return p;
  };
  ushort_t* xb    = (ushort_t*)alloc((size_t)ROWS * DMODEL * 2);
  ushort_t* WqkvT = (ushort_t*)alloc((size_t)QKVN * DMODEL * 2);
  ushort_t* W1T   = (ushort_t*)alloc((size_t)DFF * DMODEL * 2);
  ushort_t* W2T   = (ushort_t*)alloc((size_t)DMODEL * DFF * 2);
  ushort_t* QKV   = (ushort_t*)alloc((size_t)ROWS * QKVN * 2);
  ushort_t* attnb = (ushort_t*)alloc((size_t)ROWS * DMODEL * 2);
  ushort_t* x1b   = (ushort_t*)alloc((size_t)ROWS * DMODEL * 2);
  ushort_t* H1b   = (ushort_t*)alloc((size_t)ROWS * DFF * 2);
  ushort_t* ffb   = (ushort_t*)alloc((size_t)ROWS * DMODEL * 2);
  float* qkvb     = (float*)alloc(QKVN * 4);
  (void)ws_size; (void)in_sizes; (void)n_in; (void)out_size;

  dim3 b256(256);
  dim3 tb(32, 8);
  cvt_f32_bf16<<<ROWS * DMODEL / 4 / 256, b256, 0, stream>>>(x, xb, ROWS * DMODEL / 4);
  transpose_cvt<<<dim3(32, 32), tb, 0, stream>>>(Wq, WqkvT, DMODEL, DMODEL);
  transpose_cvt<<<dim3(32, 32), tb, 0, stream>>>(Wk, WqkvT + DMODEL * DMODEL, DMODEL, DMODEL);
  transpose_cvt<<<dim3(32, 32), tb, 0, stream>>>(Wv, WqkvT + 2 * DMODEL * DMODEL, DMODEL, DMODEL);
  transpose_cvt<<<dim3(DFF / 32, DMODEL / 32), tb, 0, stream>>>(W1, W1T, DMODEL, DFF);
  transpose_cvt<<<dim3(DMODEL / 32, DFF / 32), tb, 0, stream>>>(W2, W2T, DFF, DMODEL);
  concat_bias<<<4, b256, 0, stream>>>(bq, bk, bv, qkvb);

  // QKV: 256^2 8-phase, grid 16x12 = 192 (192 % 8 == 0)
  gemm256<false><<<dim3(192), dim3(512), 0, stream>>>(xb, WqkvT, qkvb, QKV,
                                                      ROWS, QKVN, DMODEL, QKVN / 256);
  attn_kernel<<<dim3(16, BB * NH), b256, 0, stream>>>(QKV, attnb);
  ln_kernel<0><<<ROWS, b256, 0, stream>>>(x, attnb, g1, be1, x1b);
  // FFN1: 256^2 8-phase, grid 16x16 = 256
  gemm256<true><<<dim3(256), dim3(512), 0, stream>>>(x1b, W1T, b1, H1b,
                                                     ROWS, DFF, DMODEL, DFF / 256);
  // FFN2: N=1024 -> 256^2 grid would be 64 blocks; keep 128^2 (grid 8x32=256)
  gemm_bt<false><<<dim3(DMODEL / 128, ROWS / 128), b256, 0, stream>>>(H1b, W2T, b2, ffb,
                                                                      ROWS, DMODEL, DFF);
  ln_kernel<1><<<ROWS, b256, 0, stream>>>(x1b, ffb, g2, be2, out);
}